// Round 9
// baseline (189.803 us; speedup 1.0000x reference)
//
#include <hip/hip_runtime.h>

typedef short s16x8 __attribute__((ext_vector_type(8)));
typedef short s16x4 __attribute__((ext_vector_type(4)));
typedef float f32x4 __attribute__((ext_vector_type(4)));
typedef float f4 __attribute__((ext_vector_type(4)));
typedef unsigned short u16x4 __attribute__((ext_vector_type(4)));

#define CEXP 14.426950408889634074f   // 10 * log2(e)

__device__ __forceinline__ unsigned short f2bf(float f) {
    union { float f; unsigned int i; } v; v.f = f;
    unsigned int x = v.i;
    return (unsigned short)((x + 0x7fffu + ((x >> 16) & 1u)) >> 16);  // RNE
}
__device__ __forceinline__ float bf2f(unsigned short u) {
    union { unsigned int i; float f; } v; v.i = ((unsigned int)u) << 16; return v.f;
}

__device__ __forceinline__ f32x4 mfma16x16x16_bf16(s16x4 a, s16x4 b, f32x4 c) {
#if __has_builtin(__builtin_amdgcn_mfma_f32_16x16x16bf16_1k)
    return __builtin_amdgcn_mfma_f32_16x16x16bf16_1k(a, b, c, 0, 0, 0);
#else
    f32x4 d = c;
    asm("v_mfma_f32_16x16x16_bf16 %0, %1, %2, %0" : "+v"(d) : "v"(a), "v"(b));
    return d;
#endif
}

// pack 4 fp32 -> 4 bf16 (element order preserved)
__device__ __forceinline__ s16x4 pk_bf16x4(float p0, float p1, float p2, float p3) {
#if __has_builtin(__builtin_amdgcn_cvt_pk_bf16_f32)
    typedef __bf16 bf16x2 __attribute__((ext_vector_type(2)));
    union { struct { bf16x2 a, b; } h; s16x4 s; } r;
    r.h.a = __builtin_amdgcn_cvt_pk_bf16_f32(p0, p1);
    r.h.b = __builtin_amdgcn_cvt_pk_bf16_f32(p2, p3);
    return r.s;
#else
    unsigned u0 = __float_as_uint(p0) + 0x8000u;
    unsigned u1 = __float_as_uint(p1) + 0x8000u;
    unsigned u2 = __float_as_uint(p2) + 0x8000u;
    unsigned u3 = __float_as_uint(p3) + 0x8000u;
    union { uint2 u; s16x4 s; } pb;
    pb.u.x = __builtin_amdgcn_perm(u1, u0, 0x07060302u);
    pb.u.y = __builtin_amdgcn_perm(u3, u2, 0x07060302u);
    return pb.s;
#endif
}

__device__ __forceinline__ u16x4 pk4(f4 v) {
    u16x4 r = { f2bf(v[0]), f2bf(v[1]), f2bf(v[2]), f2bf(v[3]) };
    return r;
}

// ---------------------------------------------------------------------------
// k_prep: xb = bf16(x); Wt[n][k] = bf16(Wqkv[k][n]); WoT[n][k] = bf16(Wout[k][n])
// ---------------------------------------------------------------------------
__global__ __launch_bounds__(256) void k_prep(
    const float* __restrict__ x, const float* __restrict__ Wqkv,
    const float* __restrict__ Wout,
    unsigned short* __restrict__ xb, unsigned short* __restrict__ Wt,
    unsigned short* __restrict__ WoT)
{
    const int blk = blockIdx.x, tid = threadIdx.x;
    if (blk < 1024) {
        int base = (blk * 256 + tid) * 8;
        f4 a = *(const f4*)&x[base];
        f4 b = *(const f4*)&x[base + 4];
        *(u16x4*)&xb[base] = pk4(a);
        *(u16x4*)&xb[base + 4] = pk4(b);
    } else if (blk < 1216) {
        int e = (blk - 1024) * 256 + tid;          // e < 49152
        int n = e >> 7, k = e & 127;
        Wt[e] = f2bf(Wqkv[k * 384 + n]);
    } else {
        int e = (blk - 1216) * 256 + tid;          // e < 16384
        int n = e >> 7, k = e & 127;
        WoT[e] = f2bf(Wout[k * 128 + n]);
    }
}

// ---------------------------------------------------------------------------
// k_qkv v3.1 (MFMA, load-all-then-compute):
//   Q/K blocks (cb<2): SWAPPED operands mfma(A=W, B=x): D row = outdim =
//     4qd+r, col = token = nn  ->  packed u16x4 stores along dims; sumsq via
//     16-lane butterfly over tokens + 4-lane distinct-address atomics.
//   V blocks  (cb==2): R7-validated orientation: D row = token, col = dim ->
//     packed u16x4 stores along tokens into Vt [bh][d][tok].
//   (R8 bug: V-branch dim dropped the (n0&127) base -> half of V aliased;
//    restored here.)
// ---------------------------------------------------------------------------
__global__ __launch_bounds__(256, 4) void k_qkv(
    const unsigned short* __restrict__ xb, const unsigned short* __restrict__ Wt,
    unsigned short* __restrict__ Qb, unsigned short* __restrict__ Kb,
    unsigned short* __restrict__ Vt, float* __restrict__ sumsq)
{
    const int tid = threadIdx.x;
    const int wl = tid >> 6, lane = tid & 63;
    const int qd = lane >> 4, nn = lane & 15;
    const int n0 = blockIdx.y * 64;            // global output col base
    const int tw0 = blockIdx.x * 64 + wl * 16; // token base for this wave

    const unsigned short* ap = xb + (size_t)(tw0 + nn) * 128 + qd * 8;
    const unsigned short* bp = Wt + (size_t)(n0 + nn) * 128 + qd * 8;
    s16x8 af[4], bfr[16];
#pragma unroll
    for (int ks = 0; ks < 4; ++ks) af[ks] = *(const s16x8*)(ap + ks * 32);
#pragma unroll
    for (int nb = 0; nb < 4; ++nb)
#pragma unroll
        for (int ks = 0; ks < 4; ++ks)
            bfr[nb * 4 + ks] = *(const s16x8*)(bp + (size_t)nb * 2048 + ks * 32);

    f32x4 acc[4];
#pragma unroll
    for (int nb = 0; nb < 4; ++nb) acc[nb] = (f32x4){0.f, 0.f, 0.f, 0.f};

    const int cb = n0 >> 7;            // 0=q 1=k 2=v
    const int b = tw0 >> 12;           // batch
    const int tl0 = tw0 & 4095;        // token within batch

    if (cb < 2) {
        // A = W rows (out-cols), B = x rows (tokens)
#pragma unroll
        for (int ks = 0; ks < 4; ++ks)
#pragma unroll
            for (int nb = 0; nb < 4; ++nb)
                acc[nb] = __builtin_amdgcn_mfma_f32_16x16x32_bf16(bfr[nb * 4 + ks], af[ks], acc[nb], 0, 0, 0);
        unsigned short* dst = (cb == 0) ? Qb : Kb;
        const int tok = tl0 + nn;
#pragma unroll
        for (int nb = 0; nb < 4; ++nb) {
            const int dim = (n0 & 127) + nb * 16 + qd * 4;   // 4-aligned, +r
            const int h = dim >> 5, d0 = dim & 31;
            *(u16x4*)&dst[(size_t)((b * 4 + h) * 4096 + tok) * 32 + d0] = pk4(acc[nb]);
            f32x4 ss;
#pragma unroll
            for (int r = 0; r < 4; ++r) ss[r] = acc[nb][r] * acc[nb][r];
#pragma unroll
            for (int m = 1; m < 16; m <<= 1) {
#pragma unroll
                for (int r = 0; r < 4; ++r) ss[r] += __shfl_xor(ss[r], m);
            }
            if (nn == 0) {
                float* sp = &sumsq[cb * 512 + (b * 4 + h) * 32 + d0];
                atomicAdd(sp + 0, ss[0]);
                atomicAdd(sp + 1, ss[1]);
                atomicAdd(sp + 2, ss[2]);
                atomicAdd(sp + 3, ss[3]);
            }
        }
    } else {
        // A = x rows (tokens), B = W rows (out-cols): D row = token = 4qd+r
#pragma unroll
        for (int ks = 0; ks < 4; ++ks)
#pragma unroll
            for (int nb = 0; nb < 4; ++nb)
                acc[nb] = __builtin_amdgcn_mfma_f32_16x16x32_bf16(af[ks], bfr[nb * 4 + ks], acc[nb], 0, 0, 0);
#pragma unroll
        for (int nb = 0; nb < 4; ++nb) {
            const int dim = (n0 & 127) + nb * 16 + nn;       // FIX: restore base
            const int h = dim >> 5, d = dim & 31;
            *(u16x4*)&Vt[(size_t)((b * 4 + h) * 32 + d) * 4096 + tl0 + qd * 4] = pk4(acc[nb]);
        }
    }
}

// ---------------------------------------------------------------------------
// k_norm v2: K only -- scale Kb by min(rsqrt(sumsq_k), 1e12).
// (Q normalization + CEXP now folded into k_attn's qfrag prep.)
// ---------------------------------------------------------------------------
__global__ __launch_bounds__(256) void k_norm(
    unsigned short* __restrict__ Kb, const float* __restrict__ sumsq)
{
    int t = blockIdx.x * 256 + threadIdx.x;   // 262144 threads, 8 elems each
    int i8 = t * 8;
    int d0 = i8 & 31;
    int bh = i8 >> 17;
    const float* sq = sumsq + 512 + bh * 32 + d0;
    union { uint4 v; unsigned short u[8]; } dat;
    dat.v = *(const uint4*)(Kb + i8);
#pragma unroll
    for (int j = 0; j < 8; ++j) {
        float r = fminf(__builtin_amdgcn_rsqf(sq[j]), 1e12f);
        dat.u[j] = f2bf(bf2f(dat.u[j]) * r);
    }
    *(uint4*)(Kb + i8) = dat.v;
}

// ---------------------------------------------------------------------------
// k_attn v5: 512 threads = 8 waves; waves 0-3 j in [0,2048), 4-7 j in
// [2048,4096).  Each wave covers TWO i-tiles (32 q-rows): one K/V LDS read
// feeds 2 QK + 4 PV MFMAs -> LDS bytes per unit work halved vs R7.
// Q-norm (+CEXP softmax scale) applied to qfrags at load from raw Qb+sumsq.
// Explicit dwordx4 -> ds_write_b128 double-buffered staging (R6-validated),
// one barrier/iter.  bf16 packing via v_cvt_pk_bf16_f32 when available.
// ---------------------------------------------------------------------------
__global__ __launch_bounds__(512, 2) void k_attn(
    const unsigned short* __restrict__ Qb, const unsigned short* __restrict__ Kb,
    const unsigned short* __restrict__ Vt, const float* __restrict__ sumsq,
    unsigned short* __restrict__ Ogb)
{
    __shared__ char smem[32768];
    const int tid  = threadIdx.x;
    const int wv   = tid >> 6, lane = tid & 63;
    const int wl   = wv & 3, half = wv >> 2;
    const int qd   = lane >> 4, nn = lane & 15;
    const int bh   = blockIdx.x;
    const int ib   = blockIdx.y * 128 + wl * 32;
    const unsigned short* Qbh = Qb + (size_t)bh * 4096 * 32;
    const unsigned short* Kbh = Kb + (size_t)bh * 4096 * 32;
    const unsigned short* Vbh = Vt + (size_t)bh * 32 * 4096;

    // Q-norm scales for dims qd*8..qd*8+7 of this bh (sumsq_q region)
    float rj[8];
    const float* sqq = sumsq + bh * 32 + qd * 8;
#pragma unroll
    for (int j = 0; j < 8; ++j)
        rj[j] = fminf(__builtin_amdgcn_rsqf(sqq[j]), 1e12f) * CEXP;

    s16x8 q0r = *(const s16x8*)(Qbh + (ib + nn) * 32 + qd * 8);
    s16x8 q1r = *(const s16x8*)(Qbh + (ib + 16 + nn) * 32 + qd * 8);
    s16x8 qf0, qf1;
#pragma unroll
    for (int j = 0; j < 8; ++j) {
        qf0[j] = (short)f2bf(bf2f((unsigned short)q0r[j]) * rj[j]);
        qf1[j] = (short)f2bf(bf2f((unsigned short)q1r[j]) * rj[j]);
    }

    f32x4 o00 = {0.f,0.f,0.f,0.f}, o01 = {0.f,0.f,0.f,0.f};
    f32x4 o10 = {0.f,0.f,0.f,0.f}, o11 = {0.f,0.f,0.f,0.f};
    const f32x4 zro = {0.f,0.f,0.f,0.f};
    float lpa = 0.f, lpb = 0.f;

    const int KB0 = half * 8192;
    const int VB0 = 16384 + half * 8192;
    const int jb0 = half * 2048;

    const unsigned short* ksrc = Kbh + (size_t)(jb0 + wl * 16 + nn) * 32 + qd * 8;
    const unsigned short* vsrc = Vbh + (size_t)(nn + 16 * (wl >> 1)) * 4096
                               + jb0 + ((wl & 1) * 2 + (qd >> 1)) * 16 + (qd & 1) * 8;
    char* kdst = smem + KB0 + wl * 1024 + lane * 16;
    char* vdst = smem + VB0 + wl * 1024 + lane * 16;

    {   // preload tile 0 -> buffer 0
        uint4 gk = *(const uint4*)ksrc;
        uint4 gv = *(const uint4*)vsrc;
        ksrc += 2048; vsrc += 64;
        *(uint4*)kdst = gk;
        *(uint4*)vdst = gv;
    }

    const int vro = (qd >> 1) * 256 + nn * 16 + (qd & 1) * 8;

    for (int jt = 0; jt < 32; ++jt) {
        uint4 ngk = *(const uint4*)ksrc;     // tile jt+1 (jt=31: in-ws, unused)
        uint4 ngv = *(const uint4*)vsrc;
        ksrc += 2048; vsrc += 64;

        __syncthreads();
        const char* kcur = smem + KB0 + (jt & 1) * 4096;
        const char* vcur = smem + VB0 + (jt & 1) * 4096;
#pragma unroll
        for (int js = 0; js < 4; ++js) {
            s16x8 kf = *(const s16x8*)(kcur + js * 1024 + lane * 16);
            f32x4 sa = __builtin_amdgcn_mfma_f32_16x16x32_bf16(kf, qf0, zro, 0, 0, 0);
            f32x4 sb = __builtin_amdgcn_mfma_f32_16x16x32_bf16(kf, qf1, zro, 0, 0, 0);
            float a0 = __builtin_amdgcn_exp2f(sa[0]);
            float a1 = __builtin_amdgcn_exp2f(sa[1]);
            float a2 = __builtin_amdgcn_exp2f(sa[2]);
            float a3 = __builtin_amdgcn_exp2f(sa[3]);
            float b0 = __builtin_amdgcn_exp2f(sb[0]);
            float b1 = __builtin_amdgcn_exp2f(sb[1]);
            float b2 = __builtin_amdgcn_exp2f(sb[2]);
            float b3 = __builtin_amdgcn_exp2f(sb[3]);
            lpa += (a0 + a1) + (a2 + a3);
            lpb += (b0 + b1) + (b2 + b3);
            s16x4 pa = pk_bf16x4(a0, a1, a2, a3);
            s16x4 pb = pk_bf16x4(b0, b1, b2, b3);
            s16x4 va = *(const s16x4*)(vcur + js * 512 + vro);
            s16x4 vb = *(const s16x4*)(vcur + 2048 + js * 512 + vro);
            o00 = mfma16x16x16_bf16(va, pa, o00);
            o01 = mfma16x16x16_bf16(vb, pa, o01);
            o10 = mfma16x16x16_bf16(va, pb, o10);
            o11 = mfma16x16x16_bf16(vb, pb, o11);
        }
        const int nxt4k = ((jt + 1) & 1) * 4096;
        *(uint4*)(kdst + nxt4k) = ngk;
        *(uint4*)(vdst + nxt4k) = ngv;
    }

    lpa += __shfl_xor(lpa, 16);
    lpa += __shfl_xor(lpa, 32);
    lpb += __shfl_xor(lpb, 16);
    lpb += __shfl_xor(lpb, 32);
    __syncthreads();                           // staging LDS dead now
    float* Ob = (float*)smem;                  // [4 wl][2 it][64 lane][8] = 16KB
    float* Lb = (float*)(smem + 16384);        // [4][2][64] = 2KB
    if (half) {
        float* d0 = Ob + ((wl * 2 + 0) * 64 + lane) * 8;
        *(f4*)d0 = o00; *(f4*)(d0 + 4) = o01;
        float* d1 = Ob + ((wl * 2 + 1) * 64 + lane) * 8;
        *(f4*)d1 = o10; *(f4*)(d1 + 4) = o11;
        Lb[(wl * 2 + 0) * 64 + lane] = lpa;
        Lb[(wl * 2 + 1) * 64 + lane] = lpb;
    }
    __syncthreads();
    if (!half) {
        const int bb = bh >> 2, hh = bh & 3;
        float* s0 = Ob + ((wl * 2 + 0) * 64 + lane) * 8;
        float rla = 1.f / (lpa + Lb[(wl * 2 + 0) * 64 + lane]);
        f4 m00 = (o00 + *(const f4*)s0) * rla;
        f4 m01 = (o01 + *(const f4*)(s0 + 4)) * rla;
        float* s1 = Ob + ((wl * 2 + 1) * 64 + lane) * 8;
        float rlb = 1.f / (lpb + Lb[(wl * 2 + 1) * 64 + lane]);
        f4 m10 = (o10 + *(const f4*)s1) * rlb;
        f4 m11 = (o11 + *(const f4*)(s1 + 4)) * rlb;
        unsigned short* dst0 = Ogb + (size_t)(bb * 4096 + blockIdx.y * 128 + wl * 32 + nn) * 128
                             + hh * 32 + qd * 4;
        *(u16x4*)dst0 = pk4(m00);
        *(u16x4*)(dst0 + 16) = pk4(m01);
        unsigned short* dst1 = dst0 + (size_t)16 * 128;
        *(u16x4*)dst1 = pk4(m10);
        *(u16x4*)(dst1 + 16) = pk4(m11);
    }
}

// ---------------------------------------------------------------------------
// k_out (MFMA, load-all-then-compute): out = Og @ W_out + b_out.
// A = WoT rows (outc), B = Og rows (tokens): D row = outc, col = token.
// ---------------------------------------------------------------------------
__global__ __launch_bounds__(256, 4) void k_out(
    const unsigned short* __restrict__ Ogb, const unsigned short* __restrict__ WoT,
    const float* __restrict__ bout, float* __restrict__ out)
{
    const int tid = threadIdx.x;
    const int wl = tid >> 6, lane = tid & 63;
    const int qd = lane >> 4, nn = lane & 15;
    const int n0 = blockIdx.y * 64;            // outc base
    const int tw0 = blockIdx.x * 64 + wl * 16; // token base

    const unsigned short* ap = WoT + (size_t)(n0 + nn) * 128 + qd * 8;
    const unsigned short* bp = Ogb + (size_t)(tw0 + nn) * 128 + qd * 8;
    s16x8 bfr[4], afr[16];
#pragma unroll
    for (int ks = 0; ks < 4; ++ks) bfr[ks] = *(const s16x8*)(bp + ks * 32);
#pragma unroll
    for (int nb = 0; nb < 4; ++nb)
#pragma unroll
        for (int ks = 0; ks < 4; ++ks)
            afr[nb * 4 + ks] = *(const s16x8*)(ap + (size_t)nb * 2048 + ks * 32);

    f32x4 acc[4];
#pragma unroll
    for (int nb = 0; nb < 4; ++nb) acc[nb] = (f32x4){0.f, 0.f, 0.f, 0.f};
#pragma unroll
    for (int ks = 0; ks < 4; ++ks)
#pragma unroll
        for (int nb = 0; nb < 4; ++nb)
            acc[nb] = __builtin_amdgcn_mfma_f32_16x16x32_bf16(afr[nb * 4 + ks], bfr[ks], acc[nb], 0, 0, 0);

#pragma unroll
    for (int nb = 0; nb < 4; ++nb) {
        const int c = n0 + nb * 16 + qd * 4;
        f4 bv = *(const f4*)&bout[c];
        f4 r;
#pragma unroll
        for (int j = 0; j < 4; ++j) r[j] = acc[nb][j] + bv[j];
        *(f4*)&out[(size_t)(tw0 + nn) * 128 + c] = r;
    }
}

// ---------------------------------------------------------------------------
extern "C" void kernel_launch(void* const* d_in, const int* in_sizes, int n_in,
                              void* d_out, int out_size, void* d_ws, size_t ws_size,
                              hipStream_t stream)
{
    const float* x    = (const float*)d_in[0];
    const float* Wqkv = (const float*)d_in[1];
    const float* Wout = (const float*)d_in[2];
    const float* bout = (const float*)d_in[3];
    float* out = (float*)d_out;
    char* ws = (char*)d_ws;
    const size_t MB = 1024 * 1024;
    unsigned short* Qb  = (unsigned short*)(ws);             // 4 MB [16][4096][32]
    unsigned short* Kb  = (unsigned short*)(ws + 4 * MB);    // 4 MB
    unsigned short* Vt  = (unsigned short*)(ws + 8 * MB);    // 4 MB [16][32][4096]
    unsigned short* Ogb = (unsigned short*)(ws + 12 * MB);   // 4 MB [16384][128] bf16
    unsigned short* xb  = (unsigned short*)(ws + 16 * MB);   // 4 MB [16384][128] bf16
    unsigned short* Wt  = (unsigned short*)(ws + 20 * MB);              // 96 KB
    unsigned short* WoT = (unsigned short*)(ws + 20 * MB + 112 * 1024); // 32 KB
    float*        sumsq = (float*)(ws + 20 * MB + 160 * 1024);          // 4 KB

    hipMemsetAsync(sumsq, 0, 4096, stream);
    hipLaunchKernelGGL(k_prep, dim3(1280), dim3(256), 0, stream, x, Wqkv, Wout, xb, Wt, WoT);
    hipLaunchKernelGGL(k_qkv, dim3(256, 6), dim3(256), 0, stream, xb, Wt, Qb, Kb, Vt, sumsq);
    hipLaunchKernelGGL(k_norm, dim3(1024), dim3(256), 0, stream, Kb, sumsq);
    hipLaunchKernelGGL(k_attn, dim3(16, 32), dim3(512), 0, stream, Qb, Kb, Vt, sumsq, Ogb);
    hipLaunchKernelGGL(k_out, dim3(256, 2), dim3(256), 0, stream, Ogb, WoT, bout, out);
}

// Round 10
// 151.287 us; speedup vs baseline: 1.2546x; 1.2546x over previous
//
#include <hip/hip_runtime.h>

typedef short s16x8 __attribute__((ext_vector_type(8)));
typedef short s16x4 __attribute__((ext_vector_type(4)));
typedef float f32x4 __attribute__((ext_vector_type(4)));
typedef float f4 __attribute__((ext_vector_type(4)));
typedef unsigned short u16x4 __attribute__((ext_vector_type(4)));

#define CEXP 14.426950408889634074f   // 10 * log2(e)

__device__ __forceinline__ unsigned short f2bf(float f) {
    union { float f; unsigned int i; } v; v.f = f;
    unsigned int x = v.i;
    return (unsigned short)((x + 0x7fffu + ((x >> 16) & 1u)) >> 16);  // RNE
}
__device__ __forceinline__ float bf2f(unsigned short u) {
    union { unsigned int i; float f; } v; v.i = ((unsigned int)u) << 16; return v.f;
}

__device__ __forceinline__ f32x4 mfma16x16x16_bf16(s16x4 a, s16x4 b, f32x4 c) {
#if __has_builtin(__builtin_amdgcn_mfma_f32_16x16x16bf16_1k)
    return __builtin_amdgcn_mfma_f32_16x16x16bf16_1k(a, b, c, 0, 0, 0);
#else
    f32x4 d = c;
    asm("v_mfma_f32_16x16x16_bf16 %0, %1, %2, %0" : "+v"(d) : "v"(a), "v"(b));
    return d;
#endif
}

// pack 4 fp32 -> 4 bf16 (element order preserved)
__device__ __forceinline__ s16x4 pk_bf16x4(float p0, float p1, float p2, float p3) {
#if __has_builtin(__builtin_amdgcn_cvt_pk_bf16_f32)
    typedef __bf16 bf16x2 __attribute__((ext_vector_type(2)));
    union { struct { bf16x2 a, b; } h; s16x4 s; } r;
    r.h.a = __builtin_amdgcn_cvt_pk_bf16_f32(p0, p1);
    r.h.b = __builtin_amdgcn_cvt_pk_bf16_f32(p2, p3);
    return r.s;
#else
    unsigned u0 = __float_as_uint(p0) + 0x8000u;
    unsigned u1 = __float_as_uint(p1) + 0x8000u;
    unsigned u2 = __float_as_uint(p2) + 0x8000u;
    unsigned u3 = __float_as_uint(p3) + 0x8000u;
    union { uint2 u; s16x4 s; } pb;
    pb.u.x = __builtin_amdgcn_perm(u1, u0, 0x07060302u);
    pb.u.y = __builtin_amdgcn_perm(u3, u2, 0x07060302u);
    return pb.s;
#endif
}

__device__ __forceinline__ u16x4 pk4(f4 v) {
    u16x4 r = { f2bf(v[0]), f2bf(v[1]), f2bf(v[2]), f2bf(v[3]) };
    return r;
}

// ---------------------------------------------------------------------------
// k_prep: xb = bf16(x); Wt[n][k] = bf16(Wqkv[k][n]); WoT[n][k] = bf16(Wout[k][n])
// ---------------------------------------------------------------------------
__global__ __launch_bounds__(256) void k_prep(
    const float* __restrict__ x, const float* __restrict__ Wqkv,
    const float* __restrict__ Wout,
    unsigned short* __restrict__ xb, unsigned short* __restrict__ Wt,
    unsigned short* __restrict__ WoT)
{
    const int blk = blockIdx.x, tid = threadIdx.x;
    if (blk < 1024) {
        int base = (blk * 256 + tid) * 8;
        f4 a = *(const f4*)&x[base];
        f4 b = *(const f4*)&x[base + 4];
        *(u16x4*)&xb[base] = pk4(a);
        *(u16x4*)&xb[base + 4] = pk4(b);
    } else if (blk < 1216) {
        int e = (blk - 1024) * 256 + tid;          // e < 49152
        int n = e >> 7, k = e & 127;
        Wt[e] = f2bf(Wqkv[k * 384 + n]);
    } else {
        int e = (blk - 1216) * 256 + tid;          // e < 16384
        int n = e >> 7, k = e & 127;
        WoT[e] = f2bf(Wout[k * 128 + n]);
    }
}

// ---------------------------------------------------------------------------
// k_qkv v4 (MFMA):
//   Q/K (cb<2): mfma(A=W, B=x): D row = outdim, col = token -> packed u16x4
//     stores; sumsq: 16-lane butterfly -> cross-wave LDS reduce -> atomics
//     SPREAD 8-way by blockIdx.x&7 into sumsqp[8][1024].
//     (R9: direct atomics serialized 1024-deep per address = 65us stall.)
//   V (cb==2): D row = token, col = dim -> packed u16x4 into Vt [bh][d][tok].
// ---------------------------------------------------------------------------
__global__ __launch_bounds__(256, 4) void k_qkv(
    const unsigned short* __restrict__ xb, const unsigned short* __restrict__ Wt,
    unsigned short* __restrict__ Qb, unsigned short* __restrict__ Kb,
    unsigned short* __restrict__ Vt, float* __restrict__ sumsqp)
{
    __shared__ float red[4][64];
    const int tid = threadIdx.x;
    const int wl = tid >> 6, lane = tid & 63;
    const int qd = lane >> 4, nn = lane & 15;
    const int n0 = blockIdx.y * 64;            // global output col base
    const int tw0 = blockIdx.x * 64 + wl * 16; // token base for this wave

    const unsigned short* ap = xb + (size_t)(tw0 + nn) * 128 + qd * 8;
    const unsigned short* bp = Wt + (size_t)(n0 + nn) * 128 + qd * 8;
    s16x8 af[4], bfr[16];
#pragma unroll
    for (int ks = 0; ks < 4; ++ks) af[ks] = *(const s16x8*)(ap + ks * 32);
#pragma unroll
    for (int nb = 0; nb < 4; ++nb)
#pragma unroll
        for (int ks = 0; ks < 4; ++ks)
            bfr[nb * 4 + ks] = *(const s16x8*)(bp + (size_t)nb * 2048 + ks * 32);

    f32x4 acc[4];
#pragma unroll
    for (int nb = 0; nb < 4; ++nb) acc[nb] = (f32x4){0.f, 0.f, 0.f, 0.f};

    const int cb = n0 >> 7;            // 0=q 1=k 2=v
    const int b = tw0 >> 12;           // batch (block-uniform: 64 | 4096)
    const int tl0 = tw0 & 4095;        // token within batch

    if (cb < 2) {
        // A = W rows (out-cols), B = x rows (tokens)
#pragma unroll
        for (int ks = 0; ks < 4; ++ks)
#pragma unroll
            for (int nb = 0; nb < 4; ++nb)
                acc[nb] = __builtin_amdgcn_mfma_f32_16x16x32_bf16(bfr[nb * 4 + ks], af[ks], acc[nb], 0, 0, 0);
        unsigned short* dst = (cb == 0) ? Qb : Kb;
        const int tok = tl0 + nn;
#pragma unroll
        for (int nb = 0; nb < 4; ++nb) {
            const int dim = (n0 & 127) + nb * 16 + qd * 4;   // 4-aligned, +r
            const int h = dim >> 5, d0 = dim & 31;
            *(u16x4*)&dst[(size_t)((b * 4 + h) * 4096 + tok) * 32 + d0] = pk4(acc[nb]);
            f32x4 ss;
#pragma unroll
            for (int r = 0; r < 4; ++r) ss[r] = acc[nb][r] * acc[nb][r];
#pragma unroll
            for (int m = 1; m < 16; m <<= 1) {
#pragma unroll
                for (int r = 0; r < 4; ++r) ss[r] += __shfl_xor(ss[r], m);
            }
            if (nn == 0)
                *(f4*)&red[wl][nb * 16 + qd * 4] = ss;   // slab partial, this wave
        }
        __syncthreads();                       // block-uniform branch: safe
        if (tid < 64) {
            float s = red[0][tid] + red[1][tid] + red[2][tid] + red[3][tid];
            // global dim slot: cb*512 + b*128 + (n0&127) + tid
            const int g = (cb << 9) + (b << 7) + (n0 & 127) + tid;
            atomicAdd(&sumsqp[((blockIdx.x & 7) << 10) + g], s);
        }
    } else {
        // A = x rows (tokens), B = W rows (out-cols): D row = token = 4qd+r
#pragma unroll
        for (int ks = 0; ks < 4; ++ks)
#pragma unroll
            for (int nb = 0; nb < 4; ++nb)
                acc[nb] = __builtin_amdgcn_mfma_f32_16x16x32_bf16(af[ks], bfr[nb * 4 + ks], acc[nb], 0, 0, 0);
#pragma unroll
        for (int nb = 0; nb < 4; ++nb) {
            const int dim = (n0 & 127) + nb * 16 + nn;
            const int h = dim >> 5, d = dim & 31;
            *(u16x4*)&Vt[(size_t)((b * 4 + h) * 32 + d) * 4096 + tl0 + qd * 4] = pk4(acc[nb]);
        }
    }
}

// ---------------------------------------------------------------------------
// k_rsum: fold the 8 spread copies; rnorm = min(rsqrt(sum),1e12), q-dims
// (slots 0..511) additionally scaled by CEXP.
// ---------------------------------------------------------------------------
__global__ __launch_bounds__(256) void k_rsum(
    const float* __restrict__ sumsqp, float* __restrict__ rnorm)
{
    int t = blockIdx.x * 256 + threadIdx.x;    // 1024 slots
    float s = 0.f;
#pragma unroll
    for (int c = 0; c < 8; ++c) s += sumsqp[c * 1024 + t];
    float r = fminf(__builtin_amdgcn_rsqf(s), 1e12f);
    if (t < 512) r *= CEXP;
    rnorm[t] = r;
}

// ---------------------------------------------------------------------------
// k_norm: scale Kb by rnorm (k region = slots 512..1023).
// ---------------------------------------------------------------------------
__global__ __launch_bounds__(256) void k_norm(
    unsigned short* __restrict__ Kb, const float* __restrict__ rnorm)
{
    int t = blockIdx.x * 256 + threadIdx.x;   // 262144 threads, 8 elems each
    int i8 = t * 8;
    int d0 = i8 & 31;
    int bh = i8 >> 17;
    const float* rp = rnorm + 512 + bh * 32 + d0;
    union { uint4 v; unsigned short u[8]; } dat;
    dat.v = *(const uint4*)(Kb + i8);
#pragma unroll
    for (int j = 0; j < 8; ++j)
        dat.u[j] = f2bf(bf2f(dat.u[j]) * rp[j]);
    *(uint4*)(Kb + i8) = dat.v;
}

// ---------------------------------------------------------------------------
// k_attn v5 (R9-validated): 512 threads = 8 waves; two j-halves, two i-tiles
// per wave; explicit dwordx4 -> ds_write_b128 double-buffered staging, one
// barrier/iter.  Q-norm scales read pre-computed from rnorm (incl. CEXP).
// ---------------------------------------------------------------------------
__global__ __launch_bounds__(512, 2) void k_attn(
    const unsigned short* __restrict__ Qb, const unsigned short* __restrict__ Kb,
    const unsigned short* __restrict__ Vt, const float* __restrict__ rnorm,
    unsigned short* __restrict__ Ogb)
{
    __shared__ char smem[32768];
    const int tid  = threadIdx.x;
    const int wv   = tid >> 6, lane = tid & 63;
    const int wl   = wv & 3, half = wv >> 2;
    const int qd   = lane >> 4, nn = lane & 15;
    const int bh   = blockIdx.x;
    const int ib   = blockIdx.y * 128 + wl * 32;
    const unsigned short* Qbh = Qb + (size_t)bh * 4096 * 32;
    const unsigned short* Kbh = Kb + (size_t)bh * 4096 * 32;
    const unsigned short* Vbh = Vt + (size_t)bh * 32 * 4096;

    float rj[8];
    const float* rp = rnorm + bh * 32 + qd * 8;
#pragma unroll
    for (int j = 0; j < 8; ++j) rj[j] = rp[j];

    s16x8 q0r = *(const s16x8*)(Qbh + (ib + nn) * 32 + qd * 8);
    s16x8 q1r = *(const s16x8*)(Qbh + (ib + 16 + nn) * 32 + qd * 8);
    s16x8 qf0, qf1;
#pragma unroll
    for (int j = 0; j < 8; ++j) {
        qf0[j] = (short)f2bf(bf2f((unsigned short)q0r[j]) * rj[j]);
        qf1[j] = (short)f2bf(bf2f((unsigned short)q1r[j]) * rj[j]);
    }

    f32x4 o00 = {0.f,0.f,0.f,0.f}, o01 = {0.f,0.f,0.f,0.f};
    f32x4 o10 = {0.f,0.f,0.f,0.f}, o11 = {0.f,0.f,0.f,0.f};
    const f32x4 zro = {0.f,0.f,0.f,0.f};
    float lpa = 0.f, lpb = 0.f;

    const int KB0 = half * 8192;
    const int VB0 = 16384 + half * 8192;
    const int jb0 = half * 2048;

    const unsigned short* ksrc = Kbh + (size_t)(jb0 + wl * 16 + nn) * 32 + qd * 8;
    const unsigned short* vsrc = Vbh + (size_t)(nn + 16 * (wl >> 1)) * 4096
                               + jb0 + ((wl & 1) * 2 + (qd >> 1)) * 16 + (qd & 1) * 8;
    char* kdst = smem + KB0 + wl * 1024 + lane * 16;
    char* vdst = smem + VB0 + wl * 1024 + lane * 16;

    {   // preload tile 0 -> buffer 0
        uint4 gk = *(const uint4*)ksrc;
        uint4 gv = *(const uint4*)vsrc;
        ksrc += 2048; vsrc += 64;
        *(uint4*)kdst = gk;
        *(uint4*)vdst = gv;
    }

    const int vro = (qd >> 1) * 256 + nn * 16 + (qd & 1) * 8;

    for (int jt = 0; jt < 32; ++jt) {
        uint4 ngk = *(const uint4*)ksrc;     // tile jt+1 (jt=31: in-ws, unused)
        uint4 ngv = *(const uint4*)vsrc;
        ksrc += 2048; vsrc += 64;

        __syncthreads();
        const char* kcur = smem + KB0 + (jt & 1) * 4096;
        const char* vcur = smem + VB0 + (jt & 1) * 4096;
#pragma unroll
        for (int js = 0; js < 4; ++js) {
            s16x8 kf = *(const s16x8*)(kcur + js * 1024 + lane * 16);
            f32x4 sa = __builtin_amdgcn_mfma_f32_16x16x32_bf16(kf, qf0, zro, 0, 0, 0);
            f32x4 sb = __builtin_amdgcn_mfma_f32_16x16x32_bf16(kf, qf1, zro, 0, 0, 0);
            float a0 = __builtin_amdgcn_exp2f(sa[0]);
            float a1 = __builtin_amdgcn_exp2f(sa[1]);
            float a2 = __builtin_amdgcn_exp2f(sa[2]);
            float a3 = __builtin_amdgcn_exp2f(sa[3]);
            float b0 = __builtin_amdgcn_exp2f(sb[0]);
            float b1 = __builtin_amdgcn_exp2f(sb[1]);
            float b2 = __builtin_amdgcn_exp2f(sb[2]);
            float b3 = __builtin_amdgcn_exp2f(sb[3]);
            lpa += (a0 + a1) + (a2 + a3);
            lpb += (b0 + b1) + (b2 + b3);
            s16x4 pa = pk_bf16x4(a0, a1, a2, a3);
            s16x4 pb = pk_bf16x4(b0, b1, b2, b3);
            s16x4 va = *(const s16x4*)(vcur + js * 512 + vro);
            s16x4 vb = *(const s16x4*)(vcur + 2048 + js * 512 + vro);
            o00 = mfma16x16x16_bf16(va, pa, o00);
            o01 = mfma16x16x16_bf16(vb, pa, o01);
            o10 = mfma16x16x16_bf16(va, pb, o10);
            o11 = mfma16x16x16_bf16(vb, pb, o11);
        }
        const int nxt4k = ((jt + 1) & 1) * 4096;
        *(uint4*)(kdst + nxt4k) = ngk;
        *(uint4*)(vdst + nxt4k) = ngv;
    }

    lpa += __shfl_xor(lpa, 16);
    lpa += __shfl_xor(lpa, 32);
    lpb += __shfl_xor(lpb, 16);
    lpb += __shfl_xor(lpb, 32);
    __syncthreads();                           // staging LDS dead now
    float* Ob = (float*)smem;                  // [4 wl][2 it][64 lane][8] = 16KB
    float* Lb = (float*)(smem + 16384);        // [4][2][64] = 2KB
    if (half) {
        float* d0 = Ob + ((wl * 2 + 0) * 64 + lane) * 8;
        *(f4*)d0 = o00; *(f4*)(d0 + 4) = o01;
        float* d1 = Ob + ((wl * 2 + 1) * 64 + lane) * 8;
        *(f4*)d1 = o10; *(f4*)(d1 + 4) = o11;
        Lb[(wl * 2 + 0) * 64 + lane] = lpa;
        Lb[(wl * 2 + 1) * 64 + lane] = lpb;
    }
    __syncthreads();
    if (!half) {
        const int bb = bh >> 2, hh = bh & 3;
        float* s0 = Ob + ((wl * 2 + 0) * 64 + lane) * 8;
        float rla = 1.f / (lpa + Lb[(wl * 2 + 0) * 64 + lane]);
        f4 m00 = (o00 + *(const f4*)s0) * rla;
        f4 m01 = (o01 + *(const f4*)(s0 + 4)) * rla;
        float* s1 = Ob + ((wl * 2 + 1) * 64 + lane) * 8;
        float rlb = 1.f / (lpb + Lb[(wl * 2 + 1) * 64 + lane]);
        f4 m10 = (o10 + *(const f4*)s1) * rlb;
        f4 m11 = (o11 + *(const f4*)(s1 + 4)) * rlb;
        unsigned short* dst0 = Ogb + (size_t)(bb * 4096 + blockIdx.y * 128 + wl * 32 + nn) * 128
                             + hh * 32 + qd * 4;
        *(u16x4*)dst0 = pk4(m00);
        *(u16x4*)(dst0 + 16) = pk4(m01);
        unsigned short* dst1 = dst0 + (size_t)16 * 128;
        *(u16x4*)dst1 = pk4(m10);
        *(u16x4*)(dst1 + 16) = pk4(m11);
    }
}

// ---------------------------------------------------------------------------
// k_out (MFMA): out = Og @ W_out + b_out.  A = WoT rows (outc), B = Og rows.
// ---------------------------------------------------------------------------
__global__ __launch_bounds__(256, 4) void k_out(
    const unsigned short* __restrict__ Ogb, const unsigned short* __restrict__ WoT,
    const float* __restrict__ bout, float* __restrict__ out)
{
    const int tid = threadIdx.x;
    const int wl = tid >> 6, lane = tid & 63;
    const int qd = lane >> 4, nn = lane & 15;
    const int n0 = blockIdx.y * 64;            // outc base
    const int tw0 = blockIdx.x * 64 + wl * 16; // token base

    const unsigned short* ap = WoT + (size_t)(n0 + nn) * 128 + qd * 8;
    const unsigned short* bp = Ogb + (size_t)(tw0 + nn) * 128 + qd * 8;
    s16x8 bfr[4], afr[16];
#pragma unroll
    for (int ks = 0; ks < 4; ++ks) bfr[ks] = *(const s16x8*)(bp + ks * 32);
#pragma unroll
    for (int nb = 0; nb < 4; ++nb)
#pragma unroll
        for (int ks = 0; ks < 4; ++ks)
            afr[nb * 4 + ks] = *(const s16x8*)(ap + (size_t)nb * 2048 + ks * 32);

    f32x4 acc[4];
#pragma unroll
    for (int nb = 0; nb < 4; ++nb) acc[nb] = (f32x4){0.f, 0.f, 0.f, 0.f};
#pragma unroll
    for (int ks = 0; ks < 4; ++ks)
#pragma unroll
        for (int nb = 0; nb < 4; ++nb)
            acc[nb] = __builtin_amdgcn_mfma_f32_16x16x32_bf16(afr[nb * 4 + ks], bfr[ks], acc[nb], 0, 0, 0);

#pragma unroll
    for (int nb = 0; nb < 4; ++nb) {
        const int c = n0 + nb * 16 + qd * 4;
        f4 bv = *(const f4*)&bout[c];
        f4 r;
#pragma unroll
        for (int j = 0; j < 4; ++j) r[j] = acc[nb][j] + bv[j];
        *(f4*)&out[(size_t)(tw0 + nn) * 128 + c] = r;
    }
}

// ---------------------------------------------------------------------------
extern "C" void kernel_launch(void* const* d_in, const int* in_sizes, int n_in,
                              void* d_out, int out_size, void* d_ws, size_t ws_size,
                              hipStream_t stream)
{
    const float* x    = (const float*)d_in[0];
    const float* Wqkv = (const float*)d_in[1];
    const float* Wout = (const float*)d_in[2];
    const float* bout = (const float*)d_in[3];
    float* out = (float*)d_out;
    char* ws = (char*)d_ws;
    const size_t MB = 1024 * 1024;
    unsigned short* Qb  = (unsigned short*)(ws);             // 4 MB [16][4096][32]
    unsigned short* Kb  = (unsigned short*)(ws + 4 * MB);    // 4 MB
    unsigned short* Vt  = (unsigned short*)(ws + 8 * MB);    // 4 MB [16][32][4096]
    unsigned short* Ogb = (unsigned short*)(ws + 12 * MB);   // 4 MB [16384][128] bf16
    unsigned short* xb  = (unsigned short*)(ws + 16 * MB);   // 4 MB [16384][128] bf16
    unsigned short* Wt  = (unsigned short*)(ws + 20 * MB);               // 96 KB
    unsigned short* WoT = (unsigned short*)(ws + 20 * MB + 112 * 1024);  // 32 KB
    float*       sumsqp = (float*)(ws + 20 * MB + 160 * 1024);           // 32 KB [8][1024]
    float*        rnorm = (float*)(ws + 20 * MB + 192 * 1024);           // 4 KB [1024]

    hipMemsetAsync(sumsqp, 0, 32768, stream);
    hipLaunchKernelGGL(k_prep, dim3(1280), dim3(256), 0, stream, x, Wqkv, Wout, xb, Wt, WoT);
    hipLaunchKernelGGL(k_qkv, dim3(256, 6), dim3(256), 0, stream, xb, Wt, Qb, Kb, Vt, sumsqp);
    hipLaunchKernelGGL(k_rsum, dim3(4), dim3(256), 0, stream, sumsqp, rnorm);
    hipLaunchKernelGGL(k_norm, dim3(1024), dim3(256), 0, stream, Kb, rnorm);
    hipLaunchKernelGGL(k_attn, dim3(16, 32), dim3(512), 0, stream, Qb, Kb, Vt, rnorm, Ogb);
    hipLaunchKernelGGL(k_out, dim3(256, 2), dim3(256), 0, stream, Ogb, WoT, bout, out);
}

// Round 11
// 148.882 us; speedup vs baseline: 1.2749x; 1.0161x over previous
//
#include <hip/hip_runtime.h>

typedef short s16x8 __attribute__((ext_vector_type(8)));
typedef short s16x4 __attribute__((ext_vector_type(4)));
typedef float f32x4 __attribute__((ext_vector_type(4)));
typedef float f4 __attribute__((ext_vector_type(4)));
typedef unsigned short u16x4 __attribute__((ext_vector_type(4)));

#define CEXP 14.426950408889634074f   // 10 * log2(e)

__device__ __forceinline__ unsigned short f2bf(float f) {
    union { float f; unsigned int i; } v; v.f = f;
    unsigned int x = v.i;
    return (unsigned short)((x + 0x7fffu + ((x >> 16) & 1u)) >> 16);  // RNE
}
__device__ __forceinline__ float bf2f(unsigned short u) {
    union { unsigned int i; float f; } v; v.i = ((unsigned int)u) << 16; return v.f;
}

__device__ __forceinline__ f32x4 mfma16x16x16_bf16(s16x4 a, s16x4 b, f32x4 c) {
#if __has_builtin(__builtin_amdgcn_mfma_f32_16x16x16bf16_1k)
    return __builtin_amdgcn_mfma_f32_16x16x16bf16_1k(a, b, c, 0, 0, 0);
#else
    f32x4 d = c;
    asm("v_mfma_f32_16x16x16_bf16 %0, %1, %2, %0" : "+v"(d) : "v"(a), "v"(b));
    return d;
#endif
}

// pack 4 fp32 -> 4 bf16 (element order preserved)
__device__ __forceinline__ s16x4 pk_bf16x4(float p0, float p1, float p2, float p3) {
#if __has_builtin(__builtin_amdgcn_cvt_pk_bf16_f32)
    typedef __bf16 bf16x2 __attribute__((ext_vector_type(2)));
    union { struct { bf16x2 a, b; } h; s16x4 s; } r;
    r.h.a = __builtin_amdgcn_cvt_pk_bf16_f32(p0, p1);
    r.h.b = __builtin_amdgcn_cvt_pk_bf16_f32(p2, p3);
    return r.s;
#else
    unsigned u0 = __float_as_uint(p0) + 0x8000u;
    unsigned u1 = __float_as_uint(p1) + 0x8000u;
    unsigned u2 = __float_as_uint(p2) + 0x8000u;
    unsigned u3 = __float_as_uint(p3) + 0x8000u;
    union { uint2 u; s16x4 s; } pb;
    pb.u.x = __builtin_amdgcn_perm(u1, u0, 0x07060302u);
    pb.u.y = __builtin_amdgcn_perm(u3, u2, 0x07060302u);
    return pb.s;
#endif
}

__device__ __forceinline__ u16x4 pk4(f4 v) {
    u16x4 r = { f2bf(v[0]), f2bf(v[1]), f2bf(v[2]), f2bf(v[3]) };
    return r;
}

// ---------------------------------------------------------------------------
// k_prep: Wt[n][k] = bf16(Wqkv[k][n]); WoT[n][k] = bf16(Wout[k][n]);
// blocks 256..287 zero sumsqp (replaces hipMemsetAsync dispatch).
// (x -> bf16 cast is folded into k_qkv's fragment loads.)
// ---------------------------------------------------------------------------
__global__ __launch_bounds__(256) void k_prep(
    const float* __restrict__ Wqkv, const float* __restrict__ Wout,
    unsigned short* __restrict__ Wt, unsigned short* __restrict__ WoT,
    float* __restrict__ sumsqp)
{
    const int blk = blockIdx.x, tid = threadIdx.x;
    if (blk < 192) {
        int e = blk * 256 + tid;                   // e < 49152
        int n = e >> 7, k = e & 127;
        Wt[e] = f2bf(Wqkv[k * 384 + n]);
    } else if (blk < 256) {
        int e = (blk - 192) * 256 + tid;           // e < 16384
        int n = e >> 7, k = e & 127;
        WoT[e] = f2bf(Wout[k * 128 + n]);
    } else {
        sumsqp[(blk - 256) * 256 + tid] = 0.f;     // 8192 floats
    }
}

// ---------------------------------------------------------------------------
// k_qkv v5 (MFMA, reads fp32 x directly -> in-register bf16 fragments):
//   Q/K (cb<2): mfma(A=W, B=x): D row = outdim, col = token -> packed u16x4
//     stores of RAW (unnormalized) q/k; sumsq: 16-lane butterfly ->
//     cross-wave LDS reduce -> atomics spread 8-way into sumsqp[8][1024].
//   V (cb==2): D row = token, col = dim -> packed u16x4 into Vt [bh][d][tok].
// ---------------------------------------------------------------------------
__global__ __launch_bounds__(256, 4) void k_qkv(
    const float* __restrict__ x, const unsigned short* __restrict__ Wt,
    unsigned short* __restrict__ Qb, unsigned short* __restrict__ Kb,
    unsigned short* __restrict__ Vt, float* __restrict__ sumsqp)
{
    __shared__ float red[4][64];
    const int tid = threadIdx.x;
    const int wl = tid >> 6, lane = tid & 63;
    const int qd = lane >> 4, nn = lane & 15;
    const int n0 = blockIdx.y * 64;            // global output col base
    const int tw0 = blockIdx.x * 64 + wl * 16; // token base for this wave

    const float* apf = x + (size_t)(tw0 + nn) * 128 + qd * 8;
    const unsigned short* bp = Wt + (size_t)(n0 + nn) * 128 + qd * 8;
    s16x8 af[4], bfr[16];
#pragma unroll
    for (int ks = 0; ks < 4; ++ks) {
        f4 a0 = *(const f4*)(apf + ks * 32);
        f4 a1 = *(const f4*)(apf + ks * 32 + 4);
        union { struct { s16x4 lo, hi; } h; s16x8 v; } u;
        u.h.lo = pk_bf16x4(a0[0], a0[1], a0[2], a0[3]);
        u.h.hi = pk_bf16x4(a1[0], a1[1], a1[2], a1[3]);
        af[ks] = u.v;
    }
#pragma unroll
    for (int nb = 0; nb < 4; ++nb)
#pragma unroll
        for (int ks = 0; ks < 4; ++ks)
            bfr[nb * 4 + ks] = *(const s16x8*)(bp + (size_t)nb * 2048 + ks * 32);

    f32x4 acc[4];
#pragma unroll
    for (int nb = 0; nb < 4; ++nb) acc[nb] = (f32x4){0.f, 0.f, 0.f, 0.f};

    const int cb = n0 >> 7;            // 0=q 1=k 2=v
    const int b = tw0 >> 12;           // batch (block-uniform: 64 | 4096)
    const int tl0 = tw0 & 4095;        // token within batch

    if (cb < 2) {
        // A = W rows (out-cols), B = x rows (tokens)
#pragma unroll
        for (int ks = 0; ks < 4; ++ks)
#pragma unroll
            for (int nb = 0; nb < 4; ++nb)
                acc[nb] = __builtin_amdgcn_mfma_f32_16x16x32_bf16(bfr[nb * 4 + ks], af[ks], acc[nb], 0, 0, 0);
        unsigned short* dst = (cb == 0) ? Qb : Kb;
        const int tok = tl0 + nn;
#pragma unroll
        for (int nb = 0; nb < 4; ++nb) {
            const int dim = (n0 & 127) + nb * 16 + qd * 4;   // 4-aligned, +r
            const int h = dim >> 5, d0 = dim & 31;
            *(u16x4*)&dst[(size_t)((b * 4 + h) * 4096 + tok) * 32 + d0] = pk4(acc[nb]);
            f32x4 ss;
#pragma unroll
            for (int r = 0; r < 4; ++r) ss[r] = acc[nb][r] * acc[nb][r];
#pragma unroll
            for (int m = 1; m < 16; m <<= 1) {
#pragma unroll
                for (int r = 0; r < 4; ++r) ss[r] += __shfl_xor(ss[r], m);
            }
            if (nn == 0)
                *(f4*)&red[wl][nb * 16 + qd * 4] = ss;   // slab partial, this wave
        }
        __syncthreads();                       // block-uniform branch: safe
        if (tid < 64) {
            float s = red[0][tid] + red[1][tid] + red[2][tid] + red[3][tid];
            const int g = (cb << 9) + (b << 7) + (n0 & 127) + tid;
            atomicAdd(&sumsqp[((blockIdx.x & 7) << 10) + g], s);
        }
    } else {
        // A = x rows (tokens), B = W rows (out-cols): D row = token = 4qd+r
#pragma unroll
        for (int ks = 0; ks < 4; ++ks)
#pragma unroll
            for (int nb = 0; nb < 4; ++nb)
                acc[nb] = __builtin_amdgcn_mfma_f32_16x16x32_bf16(af[ks], bfr[nb * 4 + ks], acc[nb], 0, 0, 0);
#pragma unroll
        for (int nb = 0; nb < 4; ++nb) {
            const int dim = (n0 & 127) + nb * 16 + nn;
            const int h = dim >> 5, d = dim & 31;
            *(u16x4*)&Vt[(size_t)((b * 4 + h) * 32 + d) * 4096 + tl0 + qd * 4] = pk4(acc[nb]);
        }
    }
}

// ---------------------------------------------------------------------------
// k_attn v6: the per-dim k-normalization is DIAGONAL in d, so it commutes
// into the q-scale: sum_d (q*rq)(k*rk) = sum_d (q*rq*rk) * k_raw.  K is
// consumed RAW -> the k_norm pass over Kb is deleted entirely.  rj (=
// rq*rk*CEXP per dim) is computed here from the 8-way-spread sumsqp.
// Core structure R9/R10-validated: 512 threads = 8 waves, two j-halves,
// two i-tiles/wave, explicit dwordx4 -> ds_write_b128 double-buffered
// staging, one barrier/iter, linear half-merge.
// ---------------------------------------------------------------------------
__global__ __launch_bounds__(512, 2) void k_attn(
    const unsigned short* __restrict__ Qb, const unsigned short* __restrict__ Kb,
    const unsigned short* __restrict__ Vt, const float* __restrict__ sumsqp,
    unsigned short* __restrict__ Ogb)
{
    __shared__ char smem[32768];
    const int tid  = threadIdx.x;
    const int wv   = tid >> 6, lane = tid & 63;
    const int wl   = wv & 3, half = wv >> 2;
    const int qd   = lane >> 4, nn = lane & 15;
    const int bh   = blockIdx.x;
    const int ib   = blockIdx.y * 128 + wl * 32;
    const unsigned short* Qbh = Qb + (size_t)bh * 4096 * 32;
    const unsigned short* Kbh = Kb + (size_t)bh * 4096 * 32;
    const unsigned short* Vbh = Vt + (size_t)bh * 32 * 4096;

    // rj[d] = min(rsqrt(ssq_q),1e12) * min(rsqrt(ssq_k),1e12) * CEXP
    float rj[8];
    {
        const int gq = bh * 32 + qd * 8;
#pragma unroll
        for (int j = 0; j < 8; ++j) {
            float sq = 0.f, sk = 0.f;
#pragma unroll
            for (int c = 0; c < 8; ++c) {
                sq += sumsqp[c * 1024 + gq + j];
                sk += sumsqp[c * 1024 + 512 + gq + j];
            }
            rj[j] = fminf(__builtin_amdgcn_rsqf(sq), 1e12f)
                  * fminf(__builtin_amdgcn_rsqf(sk), 1e12f) * CEXP;
        }
    }

    s16x8 q0r = *(const s16x8*)(Qbh + (ib + nn) * 32 + qd * 8);
    s16x8 q1r = *(const s16x8*)(Qbh + (ib + 16 + nn) * 32 + qd * 8);
    s16x8 qf0, qf1;
#pragma unroll
    for (int j = 0; j < 8; ++j) {
        qf0[j] = (short)f2bf(bf2f((unsigned short)q0r[j]) * rj[j]);
        qf1[j] = (short)f2bf(bf2f((unsigned short)q1r[j]) * rj[j]);
    }

    f32x4 o00 = {0.f,0.f,0.f,0.f}, o01 = {0.f,0.f,0.f,0.f};
    f32x4 o10 = {0.f,0.f,0.f,0.f}, o11 = {0.f,0.f,0.f,0.f};
    const f32x4 zro = {0.f,0.f,0.f,0.f};
    float lpa = 0.f, lpb = 0.f;

    const int KB0 = half * 8192;
    const int VB0 = 16384 + half * 8192;
    const int jb0 = half * 2048;

    const unsigned short* ksrc = Kbh + (size_t)(jb0 + wl * 16 + nn) * 32 + qd * 8;
    const unsigned short* vsrc = Vbh + (size_t)(nn + 16 * (wl >> 1)) * 4096
                               + jb0 + ((wl & 1) * 2 + (qd >> 1)) * 16 + (qd & 1) * 8;
    char* kdst = smem + KB0 + wl * 1024 + lane * 16;
    char* vdst = smem + VB0 + wl * 1024 + lane * 16;

    {   // preload tile 0 -> buffer 0
        uint4 gk = *(const uint4*)ksrc;
        uint4 gv = *(const uint4*)vsrc;
        ksrc += 2048; vsrc += 64;
        *(uint4*)kdst = gk;
        *(uint4*)vdst = gv;
    }

    const int vro = (qd >> 1) * 256 + nn * 16 + (qd & 1) * 8;

    for (int jt = 0; jt < 32; ++jt) {
        uint4 ngk = *(const uint4*)ksrc;     // tile jt+1 (jt=31: in-ws, unused)
        uint4 ngv = *(const uint4*)vsrc;
        ksrc += 2048; vsrc += 64;

        __syncthreads();
        const char* kcur = smem + KB0 + (jt & 1) * 4096;
        const char* vcur = smem + VB0 + (jt & 1) * 4096;
#pragma unroll
        for (int js = 0; js < 4; ++js) {
            s16x8 kf = *(const s16x8*)(kcur + js * 1024 + lane * 16);
            f32x4 sa = __builtin_amdgcn_mfma_f32_16x16x32_bf16(kf, qf0, zro, 0, 0, 0);
            f32x4 sb = __builtin_amdgcn_mfma_f32_16x16x32_bf16(kf, qf1, zro, 0, 0, 0);
            float a0 = __builtin_amdgcn_exp2f(sa[0]);
            float a1 = __builtin_amdgcn_exp2f(sa[1]);
            float a2 = __builtin_amdgcn_exp2f(sa[2]);
            float a3 = __builtin_amdgcn_exp2f(sa[3]);
            float b0 = __builtin_amdgcn_exp2f(sb[0]);
            float b1 = __builtin_amdgcn_exp2f(sb[1]);
            float b2 = __builtin_amdgcn_exp2f(sb[2]);
            float b3 = __builtin_amdgcn_exp2f(sb[3]);
            lpa += (a0 + a1) + (a2 + a3);
            lpb += (b0 + b1) + (b2 + b3);
            s16x4 pa = pk_bf16x4(a0, a1, a2, a3);
            s16x4 pb = pk_bf16x4(b0, b1, b2, b3);
            s16x4 va = *(const s16x4*)(vcur + js * 512 + vro);
            s16x4 vb = *(const s16x4*)(vcur + 2048 + js * 512 + vro);
            o00 = mfma16x16x16_bf16(va, pa, o00);
            o01 = mfma16x16x16_bf16(vb, pa, o01);
            o10 = mfma16x16x16_bf16(va, pb, o10);
            o11 = mfma16x16x16_bf16(vb, pb, o11);
        }
        const int nxt4k = ((jt + 1) & 1) * 4096;
        *(uint4*)(kdst + nxt4k) = ngk;
        *(uint4*)(vdst + nxt4k) = ngv;
    }

    lpa += __shfl_xor(lpa, 16);
    lpa += __shfl_xor(lpa, 32);
    lpb += __shfl_xor(lpb, 16);
    lpb += __shfl_xor(lpb, 32);
    __syncthreads();                           // staging LDS dead now
    float* Ob = (float*)smem;                  // [4 wl][2 it][64 lane][8] = 16KB
    float* Lb = (float*)(smem + 16384);        // [4][2][64] = 2KB
    if (half) {
        float* d0 = Ob + ((wl * 2 + 0) * 64 + lane) * 8;
        *(f4*)d0 = o00; *(f4*)(d0 + 4) = o01;
        float* d1 = Ob + ((wl * 2 + 1) * 64 + lane) * 8;
        *(f4*)d1 = o10; *(f4*)(d1 + 4) = o11;
        Lb[(wl * 2 + 0) * 64 + lane] = lpa;
        Lb[(wl * 2 + 1) * 64 + lane] = lpb;
    }
    __syncthreads();
    if (!half) {
        const int bb = bh >> 2, hh = bh & 3;
        float* s0 = Ob + ((wl * 2 + 0) * 64 + lane) * 8;
        float rla = 1.f / (lpa + Lb[(wl * 2 + 0) * 64 + lane]);
        f4 m00 = (o00 + *(const f4*)s0) * rla;
        f4 m01 = (o01 + *(const f4*)(s0 + 4)) * rla;
        float* s1 = Ob + ((wl * 2 + 1) * 64 + lane) * 8;
        float rlb = 1.f / (lpb + Lb[(wl * 2 + 1) * 64 + lane]);
        f4 m10 = (o10 + *(const f4*)s1) * rlb;
        f4 m11 = (o11 + *(const f4*)(s1 + 4)) * rlb;
        unsigned short* dst0 = Ogb + (size_t)(bb * 4096 + blockIdx.y * 128 + wl * 32 + nn) * 128
                             + hh * 32 + qd * 4;
        *(u16x4*)dst0 = pk4(m00);
        *(u16x4*)(dst0 + 16) = pk4(m01);
        unsigned short* dst1 = dst0 + (size_t)16 * 128;
        *(u16x4*)dst1 = pk4(m10);
        *(u16x4*)(dst1 + 16) = pk4(m11);
    }
}

// ---------------------------------------------------------------------------
// k_out (MFMA): out = Og @ W_out + b_out.  A = WoT rows (outc), B = Og rows.
// ---------------------------------------------------------------------------
__global__ __launch_bounds__(256, 4) void k_out(
    const unsigned short* __restrict__ Ogb, const unsigned short* __restrict__ WoT,
    const float* __restrict__ bout, float* __restrict__ out)
{
    const int tid = threadIdx.x;
    const int wl = tid >> 6, lane = tid & 63;
    const int qd = lane >> 4, nn = lane & 15;
    const int n0 = blockIdx.y * 64;            // outc base
    const int tw0 = blockIdx.x * 64 + wl * 16; // token base

    const unsigned short* ap = WoT + (size_t)(n0 + nn) * 128 + qd * 8;
    const unsigned short* bp = Ogb + (size_t)(tw0 + nn) * 128 + qd * 8;
    s16x8 bfr[4], afr[16];
#pragma unroll
    for (int ks = 0; ks < 4; ++ks) bfr[ks] = *(const s16x8*)(bp + ks * 32);
#pragma unroll
    for (int nb = 0; nb < 4; ++nb)
#pragma unroll
        for (int ks = 0; ks < 4; ++ks)
            afr[nb * 4 + ks] = *(const s16x8*)(ap + (size_t)nb * 2048 + ks * 32);

    f32x4 acc[4];
#pragma unroll
    for (int nb = 0; nb < 4; ++nb) acc[nb] = (f32x4){0.f, 0.f, 0.f, 0.f};
#pragma unroll
    for (int ks = 0; ks < 4; ++ks)
#pragma unroll
        for (int nb = 0; nb < 4; ++nb)
            acc[nb] = __builtin_amdgcn_mfma_f32_16x16x32_bf16(afr[nb * 4 + ks], bfr[ks], acc[nb], 0, 0, 0);

#pragma unroll
    for (int nb = 0; nb < 4; ++nb) {
        const int c = n0 + nb * 16 + qd * 4;
        f4 bv = *(const f4*)&bout[c];
        f4 r;
#pragma unroll
        for (int j = 0; j < 4; ++j) r[j] = acc[nb][j] + bv[j];
        *(f4*)&out[(size_t)(tw0 + nn) * 128 + c] = r;
    }
}

// ---------------------------------------------------------------------------
extern "C" void kernel_launch(void* const* d_in, const int* in_sizes, int n_in,
                              void* d_out, int out_size, void* d_ws, size_t ws_size,
                              hipStream_t stream)
{
    const float* x    = (const float*)d_in[0];
    const float* Wqkv = (const float*)d_in[1];
    const float* Wout = (const float*)d_in[2];
    const float* bout = (const float*)d_in[3];
    float* out = (float*)d_out;
    char* ws = (char*)d_ws;
    const size_t MB = 1024 * 1024;
    unsigned short* Qb  = (unsigned short*)(ws);             // 4 MB [16][4096][32] (raw q)
    unsigned short* Kb  = (unsigned short*)(ws + 4 * MB);    // 4 MB (raw k)
    unsigned short* Vt  = (unsigned short*)(ws + 8 * MB);    // 4 MB [16][32][4096]
    unsigned short* Ogb = (unsigned short*)(ws + 12 * MB);   // 4 MB [16384][128] bf16
    unsigned short* Wt  = (unsigned short*)(ws + 16 * MB);               // 96 KB
    unsigned short* WoT = (unsigned short*)(ws + 16 * MB + 112 * 1024);  // 32 KB
    float*       sumsqp = (float*)(ws + 16 * MB + 160 * 1024);           // 32 KB [8][1024]

    hipLaunchKernelGGL(k_prep, dim3(288), dim3(256), 0, stream, Wqkv, Wout, Wt, WoT, sumsqp);
    hipLaunchKernelGGL(k_qkv, dim3(256, 6), dim3(256), 0, stream, x, Wt, Qb, Kb, Vt, sumsqp);
    hipLaunchKernelGGL(k_attn, dim3(16, 32), dim3(512), 0, stream, Qb, Kb, Vt, sumsqp, Ogb);
    hipLaunchKernelGGL(k_out, dim3(256, 2), dim3(256), 0, stream, Ogb, WoT, bout, out);
}

// Round 12
// 146.808 us; speedup vs baseline: 1.2929x; 1.0141x over previous
//
#include <hip/hip_runtime.h>

typedef short s16x8 __attribute__((ext_vector_type(8)));
typedef short s16x4 __attribute__((ext_vector_type(4)));
typedef float f32x4 __attribute__((ext_vector_type(4)));
typedef float f4 __attribute__((ext_vector_type(4)));
typedef unsigned short u16x4 __attribute__((ext_vector_type(4)));

#define CEXP 14.426950408889634074f   // 10 * log2(e)

__device__ __forceinline__ unsigned short f2bf(float f) {
    union { float f; unsigned int i; } v; v.f = f;
    unsigned int x = v.i;
    return (unsigned short)((x + 0x7fffu + ((x >> 16) & 1u)) >> 16);  // RNE
}
__device__ __forceinline__ float bf2f(unsigned short u) {
    union { unsigned int i; float f; } v; v.i = ((unsigned int)u) << 16; return v.f;
}

__device__ __forceinline__ f32x4 mfma16x16x16_bf16(s16x4 a, s16x4 b, f32x4 c) {
#if __has_builtin(__builtin_amdgcn_mfma_f32_16x16x16bf16_1k)
    return __builtin_amdgcn_mfma_f32_16x16x16bf16_1k(a, b, c, 0, 0, 0);
#else
    f32x4 d = c;
    asm("v_mfma_f32_16x16x16_bf16 %0, %1, %2, %0" : "+v"(d) : "v"(a), "v"(b));
    return d;
#endif
}

// pack 4 fp32 -> 4 bf16 (element order preserved)
__device__ __forceinline__ s16x4 pk_bf16x4(float p0, float p1, float p2, float p3) {
#if __has_builtin(__builtin_amdgcn_cvt_pk_bf16_f32)
    typedef __bf16 bf16x2 __attribute__((ext_vector_type(2)));
    union { struct { bf16x2 a, b; } h; s16x4 s; } r;
    r.h.a = __builtin_amdgcn_cvt_pk_bf16_f32(p0, p1);
    r.h.b = __builtin_amdgcn_cvt_pk_bf16_f32(p2, p3);
    return r.s;
#else
    unsigned u0 = __float_as_uint(p0) + 0x8000u;
    unsigned u1 = __float_as_uint(p1) + 0x8000u;
    unsigned u2 = __float_as_uint(p2) + 0x8000u;
    unsigned u3 = __float_as_uint(p3) + 0x8000u;
    union { uint2 u; s16x4 s; } pb;
    pb.u.x = __builtin_amdgcn_perm(u1, u0, 0x07060302u);
    pb.u.y = __builtin_amdgcn_perm(u3, u2, 0x07060302u);
    return pb.s;
#endif
}

__device__ __forceinline__ u16x4 pk4(f4 v) {
    u16x4 r = { f2bf(v[0]), f2bf(v[1]), f2bf(v[2]), f2bf(v[3]) };
    return r;
}

// ---------------------------------------------------------------------------
// k_prep v2: coalesced 64x64 LDS-tile transposes (read rows coalesced ->
// tile[64][65] -> write cols coalesced); R11 did stride-1536B scalar gathers.
// blocks 0..11: Wt (2 k-tiles x 6 n-tiles); 12..15: WoT (2x2);
// 16..47: zero sumsqp.
// ---------------------------------------------------------------------------
__global__ __launch_bounds__(256) void k_prep(
    const float* __restrict__ Wqkv, const float* __restrict__ Wout,
    unsigned short* __restrict__ Wt, unsigned short* __restrict__ WoT,
    float* __restrict__ sumsqp)
{
    __shared__ float tile[64][65];
    const int blk = blockIdx.x, tid = threadIdx.x;
    if (blk >= 16) {
        sumsqp[(blk - 16) * 256 + tid] = 0.f;     // 32 blocks x 256 = 8192
        return;
    }
    const float* src;
    unsigned short* dst;
    int lds_src, k0, n0;
    if (blk < 12) {
        src = Wqkv; dst = Wt; lds_src = 384;
        k0 = (blk & 1) * 64; n0 = (blk >> 1) * 64;
    } else {
        int b = blk - 12;
        src = Wout; dst = WoT; lds_src = 128;
        k0 = (b & 1) * 64; n0 = (b >> 1) * 64;
    }
    const int c = tid & 63, r0 = tid >> 6;
#pragma unroll
    for (int i = 0; i < 16; ++i) {
        int row = i * 4 + r0;
        tile[row][c] = src[(size_t)(k0 + row) * lds_src + n0 + c];
    }
    __syncthreads();
#pragma unroll
    for (int i = 0; i < 16; ++i) {
        int n = i * 4 + r0;
        dst[(size_t)(n0 + n) * 128 + k0 + c] = f2bf(tile[c][n]);
    }
}

// ---------------------------------------------------------------------------
// k_qkv v6 (MFMA): launch_bounds (256,2) -> 256-VGPR ceiling so the 20
// hoisted fragments actually stay resident (R9's VGPR_Count=56 proved the
// (256,4) build sank loads into the MFMA chain = serial latency).
//   Q/K (cb<2): mfma(A=W, B=x): D row = outdim, col = token -> packed u16x4
//     raw q/k stores; sumsq: butterfly -> LDS -> 8-way-spread atomics.
//   V (cb==2): D row = token -> packed u16x4 into Vt [bh][d][tok].
// ---------------------------------------------------------------------------
__global__ __launch_bounds__(256, 2) void k_qkv(
    const float* __restrict__ x, const unsigned short* __restrict__ Wt,
    unsigned short* __restrict__ Qb, unsigned short* __restrict__ Kb,
    unsigned short* __restrict__ Vt, float* __restrict__ sumsqp)
{
    __shared__ float red[4][64];
    const int tid = threadIdx.x;
    const int wl = tid >> 6, lane = tid & 63;
    const int qd = lane >> 4, nn = lane & 15;
    const int n0 = blockIdx.y * 64;            // global output col base
    const int tw0 = blockIdx.x * 64 + wl * 16; // token base for this wave

    const float* apf = x + (size_t)(tw0 + nn) * 128 + qd * 8;
    const unsigned short* bp = Wt + (size_t)(n0 + nn) * 128 + qd * 8;
    s16x8 af[4], bfr[16];
#pragma unroll
    for (int ks = 0; ks < 4; ++ks) {
        f4 a0 = *(const f4*)(apf + ks * 32);
        f4 a1 = *(const f4*)(apf + ks * 32 + 4);
        union { struct { s16x4 lo, hi; } h; s16x8 v; } u;
        u.h.lo = pk_bf16x4(a0[0], a0[1], a0[2], a0[3]);
        u.h.hi = pk_bf16x4(a1[0], a1[1], a1[2], a1[3]);
        af[ks] = u.v;
    }
#pragma unroll
    for (int nb = 0; nb < 4; ++nb)
#pragma unroll
        for (int ks = 0; ks < 4; ++ks)
            bfr[nb * 4 + ks] = *(const s16x8*)(bp + (size_t)nb * 2048 + ks * 32);

    f32x4 acc[4];
#pragma unroll
    for (int nb = 0; nb < 4; ++nb) acc[nb] = (f32x4){0.f, 0.f, 0.f, 0.f};

    const int cb = n0 >> 7;            // 0=q 1=k 2=v
    const int b = tw0 >> 12;           // batch (block-uniform: 64 | 4096)
    const int tl0 = tw0 & 4095;        // token within batch

    if (cb < 2) {
        // A = W rows (out-cols), B = x rows (tokens)
#pragma unroll
        for (int ks = 0; ks < 4; ++ks)
#pragma unroll
            for (int nb = 0; nb < 4; ++nb)
                acc[nb] = __builtin_amdgcn_mfma_f32_16x16x32_bf16(bfr[nb * 4 + ks], af[ks], acc[nb], 0, 0, 0);
        unsigned short* dst = (cb == 0) ? Qb : Kb;
        const int tok = tl0 + nn;
#pragma unroll
        for (int nb = 0; nb < 4; ++nb) {
            const int dim = (n0 & 127) + nb * 16 + qd * 4;   // 4-aligned, +r
            const int h = dim >> 5, d0 = dim & 31;
            *(u16x4*)&dst[(size_t)((b * 4 + h) * 4096 + tok) * 32 + d0] = pk4(acc[nb]);
            f32x4 ss;
#pragma unroll
            for (int r = 0; r < 4; ++r) ss[r] = acc[nb][r] * acc[nb][r];
#pragma unroll
            for (int m = 1; m < 16; m <<= 1) {
#pragma unroll
                for (int r = 0; r < 4; ++r) ss[r] += __shfl_xor(ss[r], m);
            }
            if (nn == 0)
                *(f4*)&red[wl][nb * 16 + qd * 4] = ss;   // slab partial, this wave
        }
        __syncthreads();                       // block-uniform branch: safe
        if (tid < 64) {
            float s = red[0][tid] + red[1][tid] + red[2][tid] + red[3][tid];
            const int g = (cb << 9) + (b << 7) + (n0 & 127) + tid;
            atomicAdd(&sumsqp[((blockIdx.x & 7) << 10) + g], s);
        }
    } else {
        // A = x rows (tokens), B = W rows (out-cols): D row = token = 4qd+r
#pragma unroll
        for (int ks = 0; ks < 4; ++ks)
#pragma unroll
            for (int nb = 0; nb < 4; ++nb)
                acc[nb] = __builtin_amdgcn_mfma_f32_16x16x32_bf16(af[ks], bfr[nb * 4 + ks], acc[nb], 0, 0, 0);
#pragma unroll
        for (int nb = 0; nb < 4; ++nb) {
            const int dim = (n0 & 127) + nb * 16 + nn;
            const int h = dim >> 5, d = dim & 31;
            *(u16x4*)&Vt[(size_t)((b * 4 + h) * 32 + d) * 4096 + tl0 + qd * 4] = pk4(acc[nb]);
        }
    }
}

// ---------------------------------------------------------------------------
// k_attn v7: (512,4) -> 2 blocks/CU co-resident (the (512,2) decl capped
// residency at 1 block/CU: k = w*4/(B/64)).  l-sum now via an all-ones
// A-fragment MFMA: D[r][col=i] = sum_j P[i][j] accumulated across js/jt --
// replaces 8 VALU adds/js AND the end shuffle-reduce with 2 matrix-pipe ops.
// Raw-K fold (R11-validated): rj = rq*rk*CEXP from 8-way-spread sumsqp.
// Core: two j-halves, two i-tiles/wave, explicit dwordx4 -> ds_write_b128
// double-buffered staging, one barrier/iter, linear half-merge.
// ---------------------------------------------------------------------------
__global__ __launch_bounds__(512, 4) void k_attn(
    const unsigned short* __restrict__ Qb, const unsigned short* __restrict__ Kb,
    const unsigned short* __restrict__ Vt, const float* __restrict__ sumsqp,
    unsigned short* __restrict__ Ogb)
{
    __shared__ char smem[32768];
    const int tid  = threadIdx.x;
    const int wv   = tid >> 6, lane = tid & 63;
    const int wl   = wv & 3, half = wv >> 2;
    const int qd   = lane >> 4, nn = lane & 15;
    const int bh   = blockIdx.x;
    const int ib   = blockIdx.y * 128 + wl * 32;
    const unsigned short* Qbh = Qb + (size_t)bh * 4096 * 32;
    const unsigned short* Kbh = Kb + (size_t)bh * 4096 * 32;
    const unsigned short* Vbh = Vt + (size_t)bh * 32 * 4096;

    // rj[d] = min(rsqrt(ssq_q),1e12) * min(rsqrt(ssq_k),1e12) * CEXP
    float rj[8];
    {
        const int gq = bh * 32 + qd * 8;
#pragma unroll
        for (int j = 0; j < 8; ++j) {
            float sq = 0.f, sk = 0.f;
#pragma unroll
            for (int c = 0; c < 8; ++c) {
                sq += sumsqp[c * 1024 + gq + j];
                sk += sumsqp[c * 1024 + 512 + gq + j];
            }
            rj[j] = fminf(__builtin_amdgcn_rsqf(sq), 1e12f)
                  * fminf(__builtin_amdgcn_rsqf(sk), 1e12f) * CEXP;
        }
    }

    s16x8 q0r = *(const s16x8*)(Qbh + (ib + nn) * 32 + qd * 8);
    s16x8 q1r = *(const s16x8*)(Qbh + (ib + 16 + nn) * 32 + qd * 8);
    s16x8 qf0, qf1;
#pragma unroll
    for (int j = 0; j < 8; ++j) {
        qf0[j] = (short)f2bf(bf2f((unsigned short)q0r[j]) * rj[j]);
        qf1[j] = (short)f2bf(bf2f((unsigned short)q1r[j]) * rj[j]);
    }

    f32x4 o00 = {0.f,0.f,0.f,0.f}, o01 = {0.f,0.f,0.f,0.f};
    f32x4 o10 = {0.f,0.f,0.f,0.f}, o11 = {0.f,0.f,0.f,0.f};
    f32x4 la  = {0.f,0.f,0.f,0.f}, lb  = {0.f,0.f,0.f,0.f};
    const f32x4 zro = {0.f,0.f,0.f,0.f};
    const s16x4 ones1 = { (short)0x3F80, (short)0x3F80, (short)0x3F80, (short)0x3F80 };

    const int KB0 = half * 8192;
    const int VB0 = 16384 + half * 8192;
    const int jb0 = half * 2048;

    const unsigned short* ksrc = Kbh + (size_t)(jb0 + wl * 16 + nn) * 32 + qd * 8;
    const unsigned short* vsrc = Vbh + (size_t)(nn + 16 * (wl >> 1)) * 4096
                               + jb0 + ((wl & 1) * 2 + (qd >> 1)) * 16 + (qd & 1) * 8;
    char* kdst = smem + KB0 + wl * 1024 + lane * 16;
    char* vdst = smem + VB0 + wl * 1024 + lane * 16;

    {   // preload tile 0 -> buffer 0
        uint4 gk = *(const uint4*)ksrc;
        uint4 gv = *(const uint4*)vsrc;
        ksrc += 2048; vsrc += 64;
        *(uint4*)kdst = gk;
        *(uint4*)vdst = gv;
    }

    const int vro = (qd >> 1) * 256 + nn * 16 + (qd & 1) * 8;

    for (int jt = 0; jt < 32; ++jt) {
        uint4 ngk = *(const uint4*)ksrc;     // tile jt+1 (jt=31: in-ws, unused)
        uint4 ngv = *(const uint4*)vsrc;
        ksrc += 2048; vsrc += 64;

        __syncthreads();
        const char* kcur = smem + KB0 + (jt & 1) * 4096;
        const char* vcur = smem + VB0 + (jt & 1) * 4096;
#pragma unroll
        for (int js = 0; js < 4; ++js) {
            s16x8 kf = *(const s16x8*)(kcur + js * 1024 + lane * 16);
            f32x4 sa = __builtin_amdgcn_mfma_f32_16x16x32_bf16(kf, qf0, zro, 0, 0, 0);
            f32x4 sb = __builtin_amdgcn_mfma_f32_16x16x32_bf16(kf, qf1, zro, 0, 0, 0);
            float a0 = __builtin_amdgcn_exp2f(sa[0]);
            float a1 = __builtin_amdgcn_exp2f(sa[1]);
            float a2 = __builtin_amdgcn_exp2f(sa[2]);
            float a3 = __builtin_amdgcn_exp2f(sa[3]);
            float b0 = __builtin_amdgcn_exp2f(sb[0]);
            float b1 = __builtin_amdgcn_exp2f(sb[1]);
            float b2 = __builtin_amdgcn_exp2f(sb[2]);
            float b3 = __builtin_amdgcn_exp2f(sb[3]);
            s16x4 pa = pk_bf16x4(a0, a1, a2, a3);
            s16x4 pb = pk_bf16x4(b0, b1, b2, b3);
            la = mfma16x16x16_bf16(ones1, pa, la);   // row-sums of P (i = col = nn)
            lb = mfma16x16x16_bf16(ones1, pb, lb);
            s16x4 va = *(const s16x4*)(vcur + js * 512 + vro);
            s16x4 vb = *(const s16x4*)(vcur + 2048 + js * 512 + vro);
            o00 = mfma16x16x16_bf16(va, pa, o00);
            o01 = mfma16x16x16_bf16(vb, pa, o01);
            o10 = mfma16x16x16_bf16(va, pb, o10);
            o11 = mfma16x16x16_bf16(vb, pb, o11);
        }
        const int nxt4k = ((jt + 1) & 1) * 4096;
        *(uint4*)(kdst + nxt4k) = ngk;
        *(uint4*)(vdst + nxt4k) = ngv;
    }

    const float lpa = la[0];   // replicated over r and qd; exact row-sum for i=nn
    const float lpb = lb[0];
    __syncthreads();                           // staging LDS dead now
    float* Ob = (float*)smem;                  // [4 wl][2 it][64 lane][8] = 16KB
    float* Lb = (float*)(smem + 16384);        // [4][2][64] = 2KB
    if (half) {
        float* d0 = Ob + ((wl * 2 + 0) * 64 + lane) * 8;
        *(f4*)d0 = o00; *(f4*)(d0 + 4) = o01;
        float* d1 = Ob + ((wl * 2 + 1) * 64 + lane) * 8;
        *(f4*)d1 = o10; *(f4*)(d1 + 4) = o11;
        Lb[(wl * 2 + 0) * 64 + lane] = lpa;
        Lb[(wl * 2 + 1) * 64 + lane] = lpb;
    }
    __syncthreads();
    if (!half) {
        const int bb = bh >> 2, hh = bh & 3;
        float* s0 = Ob + ((wl * 2 + 0) * 64 + lane) * 8;
        float rla = 1.f / (lpa + Lb[(wl * 2 + 0) * 64 + lane]);
        f4 m00 = (o00 + *(const f4*)s0) * rla;
        f4 m01 = (o01 + *(const f4*)(s0 + 4)) * rla;
        float* s1 = Ob + ((wl * 2 + 1) * 64 + lane) * 8;
        float rlb = 1.f / (lpb + Lb[(wl * 2 + 1) * 64 + lane]);
        f4 m10 = (o10 + *(const f4*)s1) * rlb;
        f4 m11 = (o11 + *(const f4*)(s1 + 4)) * rlb;
        unsigned short* dst0 = Ogb + (size_t)(bb * 4096 + blockIdx.y * 128 + wl * 32 + nn) * 128
                             + hh * 32 + qd * 4;
        *(u16x4*)dst0 = pk4(m00);
        *(u16x4*)(dst0 + 16) = pk4(m01);
        unsigned short* dst1 = dst0 + (size_t)16 * 128;
        *(u16x4*)dst1 = pk4(m10);
        *(u16x4*)(dst1 + 16) = pk4(m11);
    }
}

// ---------------------------------------------------------------------------
// k_out (MFMA): out = Og @ W_out + b_out.  A = WoT rows (outc), B = Og rows.
// (256,2): let the 20 fragments stay in registers.
// ---------------------------------------------------------------------------
__global__ __launch_bounds__(256, 2) void k_out(
    const unsigned short* __restrict__ Ogb, const unsigned short* __restrict__ WoT,
    const float* __restrict__ bout, float* __restrict__ out)
{
    const int tid = threadIdx.x;
    const int wl = tid >> 6, lane = tid & 63;
    const int qd = lane >> 4, nn = lane & 15;
    const int n0 = blockIdx.y * 64;            // outc base
    const int tw0 = blockIdx.x * 64 + wl * 16; // token base

    const unsigned short* ap = WoT + (size_t)(n0 + nn) * 128 + qd * 8;
    const unsigned short* bp = Ogb + (size_t)(tw0 + nn) * 128 + qd * 8;
    s16x8 bfr[4], afr[16];
#pragma unroll
    for (int ks = 0; ks < 4; ++ks) bfr[ks] = *(const s16x8*)(bp + ks * 32);
#pragma unroll
    for (int nb = 0; nb < 4; ++nb)
#pragma unroll
        for (int ks = 0; ks < 4; ++ks)
            afr[nb * 4 + ks] = *(const s16x8*)(ap + (size_t)nb * 2048 + ks * 32);

    f32x4 acc[4];
#pragma unroll
    for (int nb = 0; nb < 4; ++nb) acc[nb] = (f32x4){0.f, 0.f, 0.f, 0.f};
#pragma unroll
    for (int ks = 0; ks < 4; ++ks)
#pragma unroll
        for (int nb = 0; nb < 4; ++nb)
            acc[nb] = __builtin_amdgcn_mfma_f32_16x16x32_bf16(afr[nb * 4 + ks], bfr[ks], acc[nb], 0, 0, 0);

#pragma unroll
    for (int nb = 0; nb < 4; ++nb) {
        const int c = n0 + nb * 16 + qd * 4;
        f4 bv = *(const f4*)&bout[c];
        f4 r;
#pragma unroll
        for (int j = 0; j < 4; ++j) r[j] = acc[nb][j] + bv[j];
        *(f4*)&out[(size_t)(tw0 + nn) * 128 + c] = r;
    }
}

// ---------------------------------------------------------------------------
extern "C" void kernel_launch(void* const* d_in, const int* in_sizes, int n_in,
                              void* d_out, int out_size, void* d_ws, size_t ws_size,
                              hipStream_t stream)
{
    const float* x    = (const float*)d_in[0];
    const float* Wqkv = (const float*)d_in[1];
    const float* Wout = (const float*)d_in[2];
    const float* bout = (const float*)d_in[3];
    float* out = (float*)d_out;
    char* ws = (char*)d_ws;
    const size_t MB = 1024 * 1024;
    unsigned short* Qb  = (unsigned short*)(ws);             // 4 MB [16][4096][32] (raw q)
    unsigned short* Kb  = (unsigned short*)(ws + 4 * MB);    // 4 MB (raw k)
    unsigned short* Vt  = (unsigned short*)(ws + 8 * MB);    // 4 MB [16][32][4096]
    unsigned short* Ogb = (unsigned short*)(ws + 12 * MB);   // 4 MB [16384][128] bf16
    unsigned short* Wt  = (unsigned short*)(ws + 16 * MB);               // 96 KB
    unsigned short* WoT = (unsigned short*)(ws + 16 * MB + 112 * 1024);  // 32 KB
    float*       sumsqp = (float*)(ws + 16 * MB + 160 * 1024);           // 32 KB [8][1024]

    hipLaunchKernelGGL(k_prep, dim3(48), dim3(256), 0, stream, Wqkv, Wout, Wt, WoT, sumsqp);
    hipLaunchKernelGGL(k_qkv, dim3(256, 6), dim3(256), 0, stream, x, Wt, Qb, Kb, Vt, sumsqp);
    hipLaunchKernelGGL(k_attn, dim3(16, 32), dim3(512), 0, stream, Qb, Kb, Vt, sumsqp, Ogb);
    hipLaunchKernelGGL(k_out, dim3(256, 2), dim3(256), 0, stream, Ogb, WoT, bout, out);
}